// Round 3
// baseline (810.835 us; speedup 1.0000x reference)
//
#include <hip/hip_runtime.h>
#include <hip/hip_bf16.h>
#include <stdint.h>

// Problem constants (match reference)
#define BN   4096
#define SN   200
#define EN   128
#define HN   128      // ATT_H
#define ROWS 8
#define NBLK (BN / ROWS)   // 512 persistent blocks = 2/CU on 256 CUs

typedef __attribute__((ext_vector_type(8)))  short  short8;
typedef __attribute__((ext_vector_type(16))) float  floatx16;

__device__ __forceinline__ unsigned short f2bf(float f) {
  union { float f; uint32_t u; } c; c.f = f;
  uint32_t r = c.u + 0x7fffu + ((c.u >> 16) & 1u);   // RNE
  return (unsigned short)(r >> 16);
}
__device__ __forceinline__ float bf2f(unsigned short h) {
  union { uint32_t u; float f; } c; c.u = ((uint32_t)h) << 16;
  return c.f;
}
// packed f32x2 -> bf16x2 (low = x). gfx950 has v_cvt_pk_bf16_f32.
__device__ __forceinline__ uint32_t pk2(float x, float y) {
#if defined(__has_builtin) && __has_builtin(__builtin_amdgcn_cvt_pk_bf16_f32)
  typedef __bf16 bf16x2 __attribute__((ext_vector_type(2)));
  return __builtin_bit_cast(uint32_t, __builtin_amdgcn_cvt_pk_bf16_f32(x, y));
#else
  return (uint32_t)f2bf(x) | ((uint32_t)f2bf(y) << 16);
#endif
}
__device__ __forceinline__ float bcast_lane(float v, int l) {
  return __builtin_bit_cast(float, __builtin_amdgcn_readlane(__builtin_bit_cast(int, v), l));
}

// LDS byte offset of 16B chunk g (g = e>>3) of row s, XOR-16 swizzled.
__device__ __forceinline__ int aoff(int s, int g) {
  return s * 256 + (((g ^ (s & 15)) << 4));
}

// ---------------------------------------------------------------------------
// Prep: repack W_b^T into bf16 MFMA A-fragment layout, once for all blocks.
// ---------------------------------------------------------------------------
__global__ void din_prep(const float* __restrict__ fc1w, short8* __restrict__ ws_afr) {
  const int t    = blockIdx.x & 7;
  const int wv   = blockIdx.x >> 3;
  const int lane = threadIdx.x;      // 0..63
  const int half = lane >> 5;
  const int hcol = wv * 32 + (lane & 31);
  short8 fr;
  #pragma unroll
  for (int j = 0; j < 8; ++j) {
    int e = t * 16 + half * 8 + j;
    fr[j] = (short)f2bf(fc1w[e * HN + hcol]);
  }
  ws_afr[((wv * 8 + t) << 6) + lane] = fr;
}

// ---------------------------------------------------------------------------
// Kernel 1: persistent, 8 batch rows per block, software-pipelined staging.
// While computing row r, row r+1's behavior is in flight in VGPRs.
// ---------------------------------------------------------------------------
__global__ __launch_bounds__(256, 2)
void din_main(const float* __restrict__ behavior, const float* __restrict__ cand,
              const float* __restrict__ fc1w, const float* __restrict__ fc1b,
              const float* __restrict__ fc2w, const short8* __restrict__ ws_afr,
              float* __restrict__ ws_ui) {
  __shared__ unsigned short Abuf[SN * EN];       // 51200 B bf16 behavior (swizzled)
  __shared__ float scores_s[SN];                 // 800 B
  __shared__ float attn_s[SN];                   // 800 B
  __shared__ float cvec_all[2][ROWS][HN];        // 8192 B
  __shared__ float candT[EN][ROWS];              // 4096 B  (e-major for b128 reads)
  __shared__ float ui_s[EN];                     // 512 B   -> 65600 B total

  const int tid  = threadIdx.x;
  const int b    = blockIdx.x;
  const int wv   = tid >> 6;
  const int lane = tid & 63;
  const int half = lane >> 5;
  const int l31  = lane & 31;

  if (tid < SN) scores_s[tid] = 0.f;
  if (tid < EN) ui_s[tid] = 0.f;

  // stage cand rows (4 KB contiguous) -> candT[e][r]
  {
    const float4 v = ((const float4*)(cand + (size_t)b * ROWS * EN))[tid];
    const int f = tid * 4;
    #pragma unroll
    for (int j = 0; j < 4; ++j) candT[(f + j) & 127][(f + j) >> 7] = v[j];
  }

  // ---- issue row-0 behavior loads (25 float4/thread, full row) ----
  const float* src0 = behavior + (size_t)b * ROWS * SN * EN;
  float4 va[13], vb[12];
  #pragma unroll
  for (int u = 0; u < 13; ++u) {
    int q = u * 256 + tid;
    va[u] = *(const float4*)(src0 + (q >> 5) * EN + ((q & 31) << 2));
  }
  #pragma unroll
  for (int u = 0; u < 12; ++u) {
    int q = (u + 13) * 256 + tid;
    vb[u] = *(const float4*)(src0 + (q >> 5) * EN + ((q & 31) << 2));
  }

  // A-fragments (W_b^T) and fc2 weights, L2-hot, held in regs for whole block
  short8 afr[8];
  #pragma unroll
  for (int t = 0; t < 8; ++t) afr[t] = ws_afr[((wv * 8 + t) << 6) + lane];
  float wmul[16];
  #pragma unroll
  for (int i = 0; i < 16; ++i)
    wmul[i] = fc2w[wv * 32 + (i & 3) + ((i >> 2) << 3) + (half << 2)];

  __syncthreads();   // candT ready

  // ---- cvec for all 8 rows (under row-0 load shadow) ----
  {
    const int h  = tid & 127;
    const int eh = tid >> 7;
    float p[ROWS];
    const float pb = (eh == 0) ? fc1b[h] : 0.f;
    #pragma unroll
    for (int r = 0; r < ROWS; ++r) p[r] = (r == 0) ? pb : 0.f;
    // distribute bias into p[0] only once: add per-row later via fold
    if (eh == 0) {
      #pragma unroll
      for (int r = 1; r < ROWS; ++r) p[r] = pb;
      p[0] = pb;
    }
    const float* wc = fc1w + (size_t)(EN + eh * 64) * HN + h;
    #pragma unroll 8
    for (int e = 0; e < 64; ++e) {
      float w = wc[(size_t)e * HN];
      const float4* cp = (const float4*)&candT[eh * 64 + e][0];
      float4 c0 = cp[0], c1 = cp[1];
      p[0] = fmaf(c0.x, w, p[0]); p[1] = fmaf(c0.y, w, p[1]);
      p[2] = fmaf(c0.z, w, p[2]); p[3] = fmaf(c0.w, w, p[3]);
      p[4] = fmaf(c1.x, w, p[4]); p[5] = fmaf(c1.y, w, p[5]);
      p[6] = fmaf(c1.z, w, p[6]); p[7] = fmaf(c1.w, w, p[7]);
    }
    #pragma unroll
    for (int r = 0; r < ROWS; ++r) cvec_all[eh][r][h] = p[r];
  }
  __syncthreads();
  // fold the two e-halves: cvec_all[0] += cvec_all[1]
  {
    float4* d = (float4*)&cvec_all[0][0][0];
    const float4* s2 = (const float4*)&cvec_all[1][0][0];
    float4 x = d[tid], y = s2[tid];
    x.x += y.x; x.y += y.y; x.z += y.z; x.w += y.w;
    d[tid] = x;
  }

  // ---- convert row 0 -> Abuf ----
  #pragma unroll
  for (int u = 0; u < 13; ++u) {
    int q = u * 256 + tid, s = q >> 5, e4 = (q & 31) << 2;
    uint2 pk = make_uint2(pk2(va[u].x, va[u].y), pk2(va[u].z, va[u].w));
    *(uint2*)((char*)Abuf + s * 256 + ((((e4 >> 3) ^ (s & 15))) << 4) + ((e4 & 7) << 1)) = pk;
  }
  #pragma unroll
  for (int u = 0; u < 12; ++u) {
    int q = (u + 13) * 256 + tid, s = q >> 5, e4 = (q & 31) << 2;
    uint2 pk = make_uint2(pk2(vb[u].x, vb[u].y), pk2(vb[u].z, vb[u].w));
    *(uint2*)((char*)Abuf + s * 256 + ((((e4 >> 3) ^ (s & 15))) << 4) + ((e4 & 7) << 1)) = pk;
  }
  __syncthreads();

  // ================= main pipelined loop over 8 rows =================
  for (int r = 0; r < ROWS; ++r) {
    const int row = b * ROWS + r;
    const float* srcn = src0 + (size_t)(r + 1) * SN * EN;

    // prefetch chunk A of row r+1 (latency hidden behind phase 1..ui)
    if (r < ROWS - 1) {
      #pragma unroll
      for (int u = 0; u < 13; ++u) {
        int q = u * 256 + tid;
        va[u] = *(const float4*)(srcn + (q >> 5) * EN + ((q & 31) << 2));
      }
    }

    // per-row accumulator init = cand@W_c + fc1_b (folded into MFMA C)
    float cadd[16];
    #pragma unroll
    for (int i = 0; i < 16; ++i)
      cadd[i] = cvec_all[0][r][wv * 32 + (i & 3) + ((i >> 2) << 3) + (half << 2)];

    // ---- phase 1: scores via MFMA (C cols = s, h-reduction in-lane) ----
    for (int st = 0; st < 7; ++st) {
      floatx16 acc;
      #pragma unroll
      for (int i = 0; i < 16; ++i) acc[i] = cadd[i];
      const int srow = st * 32 + l31;
      const int sr   = (srow < SN) ? srow : (SN - 1);
      #pragma unroll
      for (int t = 0; t < 8; ++t) {
        const short8 bfr = *(const short8*)((const char*)Abuf + aoff(sr, 2 * t + half));
        acc = __builtin_amdgcn_mfma_f32_32x32x16_bf16(afr[t], bfr, acc, 0, 0, 0);
      }
      float part = 0.f;
      #pragma unroll
      for (int i = 0; i < 16; ++i)
        part = fmaf(fmaxf(acc[i], 0.f), wmul[i], part);
      part += __shfl_xor(part, 32, 64);
      if (lane < 32 && srow < SN) atomicAdd(&scores_s[srow], part);
    }

    // prefetch chunk B of row r+1 (latency hidden behind softmax+ui)
    if (r < ROWS - 1) {
      #pragma unroll
      for (int u = 0; u < 12; ++u) {
        int q = (u + 13) * 256 + tid;
        vb[u] = *(const float4*)(srcn + (q >> 5) * EN + ((q & 31) << 2));
      }
    }
    __syncthreads();   // scores complete

    // ---- phase 2: softmax (wave 0), write attn_s, re-zero scores_s ----
    if (wv == 0) {
      float v0[4];
      #pragma unroll
      for (int k = 0; k < 4; ++k) {
        int s = k * 64 + lane;
        v0[k] = (s < SN) ? scores_s[s] : -3.0e38f;
      }
      float m = fmaxf(fmaxf(v0[0], v0[1]), fmaxf(v0[2], v0[3]));
      #pragma unroll
      for (int off = 32; off >= 1; off >>= 1) m = fmaxf(m, __shfl_xor(m, off, 64));
      float e0[4], sum = 0.f;
      #pragma unroll
      for (int k = 0; k < 4; ++k) { e0[k] = __expf(v0[k] - m); sum += e0[k]; }
      #pragma unroll
      for (int off = 32; off >= 1; off >>= 1) sum += __shfl_xor(sum, off, 64);
      float inv = 1.0f / sum;
      #pragma unroll
      for (int k = 0; k < 4; ++k) {
        int s = k * 64 + lane;
        if (s < SN) { attn_s[s] = e0[k] * inv; scores_s[s] = 0.f; }
      }
    }
    __syncthreads();   // attn ready

    // ---- phase 3: ui[e] = sum_s attn[s]*beh[s][e] ----
    {
      const int g  = tid & 15;
      const int sg = tid >> 4;
      float ua[8] = {0.f,0.f,0.f,0.f,0.f,0.f,0.f,0.f};
      for (int s = sg; s < SN; s += 16) {
        float a = attn_s[s];
        const short8 bv = *(const short8*)((const char*)Abuf + aoff(s, g));
        #pragma unroll
        for (int j = 0; j < 8; ++j) ua[j] = fmaf(a, bf2f((unsigned short)bv[j]), ua[j]);
      }
      #pragma unroll
      for (int j = 0; j < 8; ++j) {
        ua[j] += __shfl_xor(ua[j], 16, 64);
        ua[j] += __shfl_xor(ua[j], 32, 64);
      }
      if (lane < 16) {
        #pragma unroll
        for (int j = 0; j < 8; ++j) atomicAdd(&ui_s[(g << 3) + j], ua[j]);
      }
    }
    __syncthreads();   // ui done; all Abuf reads of row r done

    if (tid < EN) {
      ws_ui[(size_t)row * EN + tid] = ui_s[tid];
      ui_s[tid] = 0.f;
    }
    // ---- convert row r+1 -> Abuf (loads arrived during compute) ----
    if (r < ROWS - 1) {
      #pragma unroll
      for (int u = 0; u < 13; ++u) {
        int q = u * 256 + tid, s = q >> 5, e4 = (q & 31) << 2;
        uint2 pk = make_uint2(pk2(va[u].x, va[u].y), pk2(va[u].z, va[u].w));
        *(uint2*)((char*)Abuf + s * 256 + ((((e4 >> 3) ^ (s & 15))) << 4) + ((e4 & 7) << 1)) = pk;
      }
      #pragma unroll
      for (int u = 0; u < 12; ++u) {
        int q = (u + 13) * 256 + tid, s = q >> 5, e4 = (q & 31) << 2;
        uint2 pk = make_uint2(pk2(vb[u].x, vb[u].y), pk2(vb[u].z, vb[u].w));
        *(uint2*)((char*)Abuf + s * 256 + ((((e4 >> 3) ^ (s & 15))) << 4) + ((e4 & 7) << 1)) = pk;
      }
    }
    __syncthreads();
  }
}

// ---------------------------------------------------------------------------
// Kernel 2: MLP head. Block = 4 batch rows (1024 blocks, 4/CU).
// ---------------------------------------------------------------------------
__global__ __launch_bounds__(256, 4)
void din_mlp(const float* __restrict__ ws_ui, const float* __restrict__ cand,
             const float* __restrict__ w1, const float* __restrict__ b1,
             const float* __restrict__ w2, const float* __restrict__ b2,
             float* __restrict__ out) {
  const int tid  = threadIdx.x;
  const int lane = tid & 63;
  const int wv   = tid >> 6;
  const int r0   = blockIdx.x * 4;

  float xr[4][4];
  #pragma unroll
  for (int r = 0; r < 4; ++r) {
    #pragma unroll
    for (int c = 0; c < 4; ++c) {
      int i = c * 64 + lane;
      int row = r0 + r;
      xr[r][c] = (i < 128) ? ws_ui[row * 128 + i] : cand[row * 128 + (i - 128)];
    }
  }

  const int j = tid;
  const float bj = b1[j];
  float acc[4] = {bj, bj, bj, bj};

  #pragma unroll
  for (int c = 0; c < 4; ++c) {
    #pragma unroll 8
    for (int il = 0; il < 64; ++il) {
      float w = w1[(c * 64 + il) * 256 + j];
      #pragma unroll
      for (int r = 0; r < 4; ++r)
        acc[r] = fmaf(bcast_lane(xr[r][c], il), w, acc[r]);
    }
  }

  const float w2j = w2[j];
  float part[4];
  #pragma unroll
  for (int r = 0; r < 4; ++r) part[r] = fmaxf(acc[r], 0.f) * w2j;
  #pragma unroll
  for (int off = 32; off >= 1; off >>= 1) {
    #pragma unroll
    for (int r = 0; r < 4; ++r) part[r] += __shfl_xor(part[r], off, 64);
  }

  __shared__ float red[4][4];
  if (lane == 0) {
    #pragma unroll
    for (int r = 0; r < 4; ++r) red[wv][r] = part[r];
  }
  __syncthreads();
  if (tid < 4)
    out[r0 + tid] = red[0][tid] + red[1][tid] + red[2][tid] + red[3][tid] + b2[0];
}

extern "C" void kernel_launch(void* const* d_in, const int* in_sizes, int n_in,
                              void* d_out, int out_size, void* d_ws, size_t ws_size,
                              hipStream_t stream) {
  const float* behavior = (const float*)d_in[0];
  const float* cand     = (const float*)d_in[1];
  const float* fc1w     = (const float*)d_in[2];
  const float* fc1b     = (const float*)d_in[3];
  const float* fc2w     = (const float*)d_in[4];
  // d_in[5] = fc2_b: constant shift before softmax -> softmax-invariant, skipped
  const float* m1w      = (const float*)d_in[6];
  const float* m1b      = (const float*)d_in[7];
  const float* m2w      = (const float*)d_in[8];
  const float* m2b      = (const float*)d_in[9];
  float* outp  = (float*)d_out;
  float* ws_ui = (float*)d_ws;                                   // 2 MB
  short8* ws_afr = (short8*)((char*)d_ws + (size_t)BN * EN * 4); // 32 KB

  din_prep<<<32, 64, 0, stream>>>(fc1w, ws_afr);
  din_main<<<NBLK, 256, 0, stream>>>(behavior, cand, fc1w, fc1b, fc2w, ws_afr, ws_ui);
  din_mlp<<<BN / 4, 256, 0, stream>>>(ws_ui, cand, m1w, m1b, m2w, m2b, outp);
}

// Round 4
// 694.992 us; speedup vs baseline: 1.1667x; 1.1667x over previous
//
#include <hip/hip_runtime.h>
#include <hip/hip_bf16.h>
#include <stdint.h>

// Problem constants (match reference)
#define BN   4096
#define SN   200
#define EN   128
#define HN   128      // ATT_H
#define ROWS 16
#define NBLK (BN / ROWS)   // 256 blocks -> 1 per CU (LDS-forced)

typedef __attribute__((ext_vector_type(8)))  short  short8;
typedef __attribute__((ext_vector_type(16))) float  floatx16;

__device__ __forceinline__ unsigned short f2bf(float f) {
  union { float f; uint32_t u; } c; c.f = f;
  uint32_t r = c.u + 0x7fffu + ((c.u >> 16) & 1u);   // RNE
  return (unsigned short)(r >> 16);
}
__device__ __forceinline__ float bf2f(unsigned short h) {
  union { uint32_t u; float f; } c; c.u = ((uint32_t)h) << 16;
  return c.f;
}
__device__ __forceinline__ uint32_t pk2(float x, float y) {
#if defined(__has_builtin) && __has_builtin(__builtin_amdgcn_cvt_pk_bf16_f32)
  typedef __bf16 bf16x2 __attribute__((ext_vector_type(2)));
  return __builtin_bit_cast(uint32_t, __builtin_amdgcn_cvt_pk_bf16_f32(x, y));
#else
  return (uint32_t)f2bf(x) | ((uint32_t)f2bf(y) << 16);
#endif
}

// LDS byte offset of 16B chunk g (g = e>>3) of row s, XOR-16 swizzled.
__device__ __forceinline__ int aoff(int s, int g) {
  return s * 256 + (((g ^ (s & 15)) << 4));
}

// async global->LDS: wave wv owns 1KB chunks c == wv (mod 8); 16B/lane, no VGPR staging
__device__ __forceinline__ void issue_row(const float* __restrict__ src,
                                          float* stage, int wv, int lane) {
  #pragma unroll
  for (int k = 0; k < 13; ++k) {
    int c = wv + k * 8;
    if (c < 100) {
      const float* g = src + c * 256 + lane * 4;
      __builtin_amdgcn_global_load_lds(
          (const __attribute__((address_space(1))) void*)g,
          (__attribute__((address_space(3))) void*)(stage + c * 256),
          16, 0, 0);
    }
  }
}

// ---------------------------------------------------------------------------
// Prep: repack W_b^T into bf16 MFMA A-fragment layout, once.
// ---------------------------------------------------------------------------
__global__ void din_prep(const float* __restrict__ fc1w, short8* __restrict__ ws_afr) {
  const int t    = blockIdx.x & 7;
  const int wv   = blockIdx.x >> 3;
  const int lane = threadIdx.x;      // 0..63
  const int half = lane >> 5;
  const int hcol = wv * 32 + (lane & 31);
  short8 fr;
  #pragma unroll
  for (int j = 0; j < 8; ++j) {
    int e = t * 16 + half * 8 + j;
    fr[j] = (short)f2bf(fc1w[e * HN + hcol]);
  }
  ws_afr[((wv * 8 + t) << 6) + lane] = fr;
}

// ---------------------------------------------------------------------------
// Fused persistent kernel: 1 block/CU, 16 rows/block.
// Row r computes from bf16 Abuf while row r+1 streams (global_load_lds) into
// fp32 stage. Per-wave wait/convert/reissue keeps HBM continuously busy.
// ---------------------------------------------------------------------------
__global__ __launch_bounds__(512, 2)
void din_fused(const float* __restrict__ behavior, const float* __restrict__ cand,
               const float* __restrict__ fc1w, const float* __restrict__ fc1b,
               const float* __restrict__ fc2w, const float* __restrict__ m1w,
               const float* __restrict__ m1b, const float* __restrict__ m2w,
               const float* __restrict__ m2b, const short8* __restrict__ ws_afr,
               float* __restrict__ out) {
  __shared__ float          stage[SN * EN];    // 102400 B fp32 next-row stream
  __shared__ unsigned short Abuf[SN * EN];     //  51200 B bf16 current row
  __shared__ float          cvec2[4][HN];      //   2048 B
  __shared__ float          scores_s[SN];      //    800 B (scores, then attn)
  __shared__ float          ui_s[EN];          //    512 B
  __shared__ float          cand_row[EN];      //    512 B
  __shared__ float          zpart[256];        //   1024 B
  __shared__ float          red[4];            //     16 B  -> 158512 B

  const int tid  = threadIdx.x;
  const int b    = blockIdx.x;
  const int wv   = tid >> 6;
  const int lane = tid & 63;
  const int half = lane >> 5;
  const int l31  = lane & 31;
  const int ht   = wv & 3;                     // h-tile of this wave
  const float* src0 = behavior + (size_t)b * ROWS * SN * EN;

  // start HBM stream of row 0 immediately
  issue_row(src0, stage, wv, lane);

  // per-block constants into registers (arrive under the stream)
  short8 afr[8];
  #pragma unroll
  for (int t = 0; t < 8; ++t) afr[t] = ws_afr[((ht * 8 + t) << 6) + lane];
  float wmul[16];
  #pragma unroll
  for (int i = 0; i < 16; ++i)
    wmul[i] = fc2w[ht * 32 + (i & 3) + ((i >> 2) << 3) + (half << 2)];
  const int   jj  = tid & 255;                 // MLP output column
  const int   ehm = tid >> 8;                  // MLP input half
  const float b1j = m1b[jj];
  const float w2j = m2w[jj];
  const float b2s = m2b[0];
  const float fb  = fc1b[tid & 127];

  if (tid < SN) scores_s[tid] = 0.f;
  if (tid < EN) {
    ui_s[tid]     = 0.f;
    cand_row[tid] = cand[(size_t)b * ROWS * EN + tid];
  }

  // wave-local: wait row 0, convert own chunks fp32->bf16, issue row 1
  asm volatile("s_waitcnt vmcnt(0)" ::: "memory");
  #pragma unroll
  for (int it = 0; it < 13; ++it) {
    int q = it * 512 + tid;
    if (it < 12 || tid < 256) {
      float4 v = *(const float4*)&stage[q * 4];
      int s = q >> 5, e4 = (q & 31) << 2;
      uint2 pk = make_uint2(pk2(v.x, v.y), pk2(v.z, v.w));
      *(uint2*)((char*)Abuf + s * 256 + ((((e4 >> 3) ^ (s & 15))) << 4) + ((e4 & 7) << 1)) = pk;
    }
  }
  if (ROWS > 1) issue_row(src0 + (size_t)SN * EN, stage, wv, lane);
  __syncthreads();

  // ================= main loop over 16 rows =================
  for (int r = 0; r < ROWS; ++r) {
    const size_t row = (size_t)b * ROWS + r;

    // ---- cvec = cand_row @ W_c + fc1_b (4 e-quarters, fold) ----
    {
      const int h = tid & 127, eq = tid >> 7;
      float p = (eq == 0) ? fb : 0.f;
      const float* wc = fc1w + (size_t)(EN + eq * 32) * HN + h;
      #pragma unroll 8
      for (int e = 0; e < 32; ++e)
        p = fmaf(cand_row[eq * 32 + e], wc[(size_t)e * HN], p);
      cvec2[eq][h] = p;
    }
    __syncthreads();
    if (tid < HN)
      cvec2[0][tid] += cvec2[1][tid] + cvec2[2][tid] + cvec2[3][tid];
    __syncthreads();

    // cadd: lane's 16 C/D rows, 4x b128 from cvec2[0]
    float cadd[16];
    {
      const float4* cb = (const float4*)&cvec2[0][ht * 32 + (half << 2)];
      #pragma unroll
      for (int blk = 0; blk < 4; ++blk) {
        float4 v = cb[blk * 2];
        cadd[blk * 4 + 0] = v.x; cadd[blk * 4 + 1] = v.y;
        cadd[blk * 4 + 2] = v.z; cadd[blk * 4 + 3] = v.w;
      }
    }

    // ---- phase 1: scores via MFMA; waves split s-tiles by parity ----
    for (int st = (wv >> 2); st < 7; st += 2) {
      floatx16 acc;
      #pragma unroll
      for (int i = 0; i < 16; ++i) acc[i] = cadd[i];
      const int srow = st * 32 + l31;
      const int sr   = (srow < SN) ? srow : (SN - 1);
      #pragma unroll
      for (int t = 0; t < 8; ++t) {
        const short8 bfr = *(const short8*)((const char*)Abuf + aoff(sr, 2 * t + half));
        acc = __builtin_amdgcn_mfma_f32_32x32x16_bf16(afr[t], bfr, acc, 0, 0, 0);
      }
      float part = 0.f;
      #pragma unroll
      for (int i = 0; i < 16; ++i)
        part = fmaf(fmaxf(acc[i], 0.f), wmul[i], part);
      part += __shfl_xor(part, 32, 64);
      if (lane < 32 && srow < SN) atomicAdd(&scores_s[srow], part);
    }
    __syncthreads();

    // ---- phase 2: softmax in place (wave 0) ----
    if (wv == 0) {
      float v0[4];
      #pragma unroll
      for (int k = 0; k < 4; ++k) {
        int s = k * 64 + lane;
        v0[k] = (s < SN) ? scores_s[s] : -3.0e38f;
      }
      float m = fmaxf(fmaxf(v0[0], v0[1]), fmaxf(v0[2], v0[3]));
      #pragma unroll
      for (int off = 32; off >= 1; off >>= 1) m = fmaxf(m, __shfl_xor(m, off, 64));
      float e0[4], sum = 0.f;
      #pragma unroll
      for (int k = 0; k < 4; ++k) { e0[k] = __expf(v0[k] - m); sum += e0[k]; }
      #pragma unroll
      for (int off = 32; off >= 1; off >>= 1) sum += __shfl_xor(sum, off, 64);
      float inv = 1.0f / sum;
      #pragma unroll
      for (int k = 0; k < 4; ++k) {
        int s = k * 64 + lane;
        if (s < SN) scores_s[s] = e0[k] * inv;   // attn in place
      }
    }
    __syncthreads();

    // ---- phase 3: ui[e] = sum_s attn[s]*beh[s][e] ----
    {
      const int g  = tid & 15;
      const int sg = tid >> 4;                   // 0..31
      float ua[8] = {0.f,0.f,0.f,0.f,0.f,0.f,0.f,0.f};
      for (int s = sg; s < SN; s += 32) {
        float a = scores_s[s];
        const short8 bv = *(const short8*)((const char*)Abuf + aoff(s, g));
        #pragma unroll
        for (int j = 0; j < 8; ++j) ua[j] = fmaf(a, bf2f((unsigned short)bv[j]), ua[j]);
      }
      #pragma unroll
      for (int j = 0; j < 8; ++j) {
        ua[j] += __shfl_xor(ua[j], 16, 64);
        ua[j] += __shfl_xor(ua[j], 32, 64);
      }
      if (lane < 16) {
        #pragma unroll
        for (int j = 0; j < 8; ++j) atomicAdd(&ui_s[(g << 3) + j], ua[j]);
      }
    }
    // prefetch next row's cand into a register (latency under barriers)
    float creg = 0.f;
    if (r + 1 < ROWS && tid < EN) creg = cand[(row + 1) * EN + tid];
    __syncthreads();   // ui complete; Abuf reads done

    // ---- fused MLP: logit[row] ----
    {
      float acc = (ehm == 0) ? b1j : 0.f;
      const float* wp = m1w + (size_t)(ehm * 128) * 256 + jj;
      #pragma unroll 8
      for (int ii = 0; ii < 128; ++ii) {
        float x = (ehm == 0) ? ui_s[ii] : cand_row[ii];
        acc = fmaf(x, wp[(size_t)ii * 256], acc);
      }
      if (ehm == 1) zpart[jj] = acc;
      __syncthreads();
      if (ehm == 0) {
        float z = fmaxf(acc + zpart[jj], 0.f);
        float part = z * w2j;
        #pragma unroll
        for (int off = 32; off >= 1; off >>= 1) part += __shfl_xor(part, off, 64);
        if (lane == 0) red[wv] = part;
      }
      __syncthreads();
      if (tid == 0) out[row] = red[0] + red[1] + red[2] + red[3] + b2s;
    }

    // ---- pipeline: wait row r+1, convert own chunks, issue row r+2 ----
    if (r + 1 < ROWS) {
      asm volatile("s_waitcnt vmcnt(0)" ::: "memory");
      #pragma unroll
      for (int it = 0; it < 13; ++it) {
        int q = it * 512 + tid;
        if (it < 12 || tid < 256) {
          float4 v = *(const float4*)&stage[q * 4];
          int s = q >> 5, e4 = (q & 31) << 2;
          uint2 pk = make_uint2(pk2(v.x, v.y), pk2(v.z, v.w));
          *(uint2*)((char*)Abuf + s * 256 + ((((e4 >> 3) ^ (s & 15))) << 4) + ((e4 & 7) << 1)) = pk;
        }
      }
      if (r + 2 < ROWS) issue_row(src0 + (size_t)(r + 2) * SN * EN, stage, wv, lane);
      if (tid < SN) scores_s[tid] = 0.f;
      if (tid < EN) { ui_s[tid] = 0.f; cand_row[tid] = creg; }
    }
    __syncthreads();
  }
}

extern "C" void kernel_launch(void* const* d_in, const int* in_sizes, int n_in,
                              void* d_out, int out_size, void* d_ws, size_t ws_size,
                              hipStream_t stream) {
  const float* behavior = (const float*)d_in[0];
  const float* cand     = (const float*)d_in[1];
  const float* fc1w     = (const float*)d_in[2];
  const float* fc1b     = (const float*)d_in[3];
  const float* fc2w     = (const float*)d_in[4];
  // d_in[5] = fc2_b: constant shift before softmax -> softmax-invariant, skipped
  const float* m1w      = (const float*)d_in[6];
  const float* m1b      = (const float*)d_in[7];
  const float* m2w      = (const float*)d_in[8];
  const float* m2b      = (const float*)d_in[9];
  float* outp    = (float*)d_out;
  short8* ws_afr = (short8*)d_ws;   // 32 KB of workspace

  din_prep<<<32, 64, 0, stream>>>(fc1w, ws_afr);
  din_fused<<<NBLK, 512, 0, stream>>>(behavior, cand, fc1w, fc1b, fc2w,
                                      m1w, m1b, m2w, m2b, ws_afr, outp);
}

// Round 5
// 607.272 us; speedup vs baseline: 1.3352x; 1.1445x over previous
//
#include <hip/hip_runtime.h>
#include <hip/hip_bf16.h>
#include <stdint.h>

// Problem constants (match reference)
#define BN   4096
#define SN   200
#define EN   128
#define HN   128      // ATT_H

typedef __attribute__((ext_vector_type(8)))  short  short8;
typedef __attribute__((ext_vector_type(16))) float  floatx16;

__device__ __forceinline__ unsigned short f2bf(float f) {
  union { float f; uint32_t u; } c; c.f = f;
  uint32_t r = c.u + 0x7fffu + ((c.u >> 16) & 1u);   // RNE
  return (unsigned short)(r >> 16);
}
__device__ __forceinline__ float bf2f(unsigned short h) {
  union { uint32_t u; float f; } c; c.u = ((uint32_t)h) << 16;
  return c.f;
}
__device__ __forceinline__ uint32_t pk2(float x, float y) {
#if defined(__has_builtin) && __has_builtin(__builtin_amdgcn_cvt_pk_bf16_f32)
  typedef __bf16 bf16x2 __attribute__((ext_vector_type(2)));
  return __builtin_bit_cast(uint32_t, __builtin_amdgcn_cvt_pk_bf16_f32(x, y));
#else
  return (uint32_t)f2bf(x) | ((uint32_t)f2bf(y) << 16);
#endif
}
__device__ __forceinline__ float bcast_lane(float v, int l) {
  return __builtin_bit_cast(float, __builtin_amdgcn_readlane(__builtin_bit_cast(int, v), l));
}

// LDS byte offset of 16B chunk g (g = e>>3) of row s, XOR-16 swizzled.
__device__ __forceinline__ int aoff(int s, int g) {
  return s * 256 + (((g ^ (s & 15)) << 4));
}

// ---------------------------------------------------------------------------
// Prep: repack W_b^T into bf16 MFMA A-fragment layout, once.
// ---------------------------------------------------------------------------
__global__ void din_prep(const float* __restrict__ fc1w, short8* __restrict__ ws_afr) {
  const int t    = blockIdx.x & 7;
  const int wv   = blockIdx.x >> 3;
  const int lane = threadIdx.x;      // 0..63
  const int half = lane >> 5;
  const int hcol = wv * 32 + (lane & 31);
  short8 fr;
  #pragma unroll
  for (int j = 0; j < 8; ++j) {
    int e = t * 16 + half * 8 + j;
    fr[j] = (short)f2bf(fc1w[e * HN + hcol]);
  }
  ws_afr[((wv * 8 + t) << 6) + lane] = fr;
}

// ---------------------------------------------------------------------------
// Kernel A: one block = one batch row. Non-persistent; 4096 blocks, 3/CU.
// Dispatcher back-fill staggers block lifetimes -> staging of fresh blocks
// overlaps compute of resident ones (no persistent-loop convoy).
// ---------------------------------------------------------------------------
__global__ __launch_bounds__(256, 3)
void din_attn(const float* __restrict__ behavior, const float* __restrict__ cand,
              const float* __restrict__ fc1w, const float* __restrict__ fc1b,
              const float* __restrict__ fc2w, const short8* __restrict__ ws_afr,
              float* __restrict__ ws_ui) {
  __shared__ unsigned short Abuf[SN * EN];     // 51200 B bf16 behavior (swizzled)
  __shared__ float scores_s[SN];               //   800 B (scores, then attn)
  __shared__ float cvec2[2][HN];               //  1024 B
  __shared__ float cand_s[EN];                 //   512 B
  __shared__ float ui_s[EN];                   //   512 B   -> 54048 B total

  const int tid  = threadIdx.x;
  const int b    = blockIdx.x;                 // batch row
  const int wv   = tid >> 6;                   // wave = h-tile
  const int lane = tid & 63;
  const int half = lane >> 5;
  const int l31  = lane & 31;

  if (tid < SN) scores_s[tid] = 0.f;
  if (tid < EN) {
    cand_s[tid] = cand[(size_t)b * EN + tid];
    ui_s[tid]   = 0.f;
  }
  __syncthreads();                             // cand_s ready

  // ---- issue staging batch A (13 float4/thread) ----
  const float* src = behavior + (size_t)b * SN * EN;
  float4 va[13];
  #pragma unroll
  for (int u = 0; u < 13; ++u) {
    int q = u * 256 + tid;
    va[u] = *(const float4*)(src + (q >> 5) * EN + ((q & 31) << 2));
  }
  // A-fragments (W_b^T, L2-hot b128) under the HBM shadow
  short8 afr[8];
  #pragma unroll
  for (int t = 0; t < 8; ++t) afr[t] = ws_afr[((wv * 8 + t) << 6) + lane];

  // ---- cvec = cand . W_c + fc1_b (under the HBM shadow) ----
  {
    const int h  = tid & 127;
    const int eh = tid >> 7;
    float p0 = (eh == 0) ? fc1b[h] : 0.f, p1 = 0.f;
    const float* wc = fc1w + (size_t)(EN + eh * 64) * HN + h;
    #pragma unroll 8
    for (int e = 0; e < 64; e += 2) {
      p0 = fmaf(cand_s[eh * 64 + e],     wc[(size_t)e * HN],       p0);
      p1 = fmaf(cand_s[eh * 64 + e + 1], wc[(size_t)(e + 1) * HN], p1);
    }
    cvec2[eh][h] = p0 + p1;
  }

  // ---- convert batch A -> Abuf (waitcnt inserted by compiler) ----
  #pragma unroll
  for (int u = 0; u < 13; ++u) {
    int q = u * 256 + tid, s = q >> 5, e4 = (q & 31) << 2;
    uint2 pk = make_uint2(pk2(va[u].x, va[u].y), pk2(va[u].z, va[u].w));
    *(uint2*)((char*)Abuf + s * 256 + ((((e4 >> 3) ^ (s & 15))) << 4) + ((e4 & 7) << 1)) = pk;
  }
  // ---- issue + convert batch B (12 float4/thread) ----
  float4 vb[12];
  #pragma unroll
  for (int u = 0; u < 12; ++u) {
    int q = (u + 13) * 256 + tid;
    vb[u] = *(const float4*)(src + (q >> 5) * EN + ((q & 31) << 2));
  }
  __syncthreads();                             // cvec2 halves written
  if (tid < HN) cvec2[0][tid] += cvec2[1][tid];
  #pragma unroll
  for (int u = 0; u < 12; ++u) {
    int q = (u + 13) * 256 + tid, s = q >> 5, e4 = (q & 31) << 2;
    uint2 pk = make_uint2(pk2(vb[u].x, vb[u].y), pk2(vb[u].z, vb[u].w));
    *(uint2*)((char*)Abuf + s * 256 + ((((e4 >> 3) ^ (s & 15))) << 4) + ((e4 & 7) << 1)) = pk;
  }
  __syncthreads();                             // Abuf + cvec fold complete

  // ---- phase 1: scores via MFMA (C cols = s; h-reduction in-lane) ----
  float cadd[16], wmul[16];
  #pragma unroll
  for (int i = 0; i < 16; ++i) {
    int hr = wv * 32 + (i & 3) + ((i >> 2) << 3) + (half << 2);
    cadd[i] = cvec2[0][hr];
    wmul[i] = fc2w[hr];
  }
  for (int st = 0; st < 7; ++st) {
    floatx16 acc;
    #pragma unroll
    for (int i = 0; i < 16; ++i) acc[i] = cadd[i];
    const int srow = st * 32 + l31;
    const int sr   = (srow < SN) ? srow : (SN - 1);
    #pragma unroll
    for (int t = 0; t < 8; ++t) {
      const short8 bfr = *(const short8*)((const char*)Abuf + aoff(sr, 2 * t + half));
      acc = __builtin_amdgcn_mfma_f32_32x32x16_bf16(afr[t], bfr, acc, 0, 0, 0);
    }
    float part = 0.f;
    #pragma unroll
    for (int i = 0; i < 16; ++i)
      part = fmaf(fmaxf(acc[i], 0.f), wmul[i], part);
    part += __shfl_xor(part, 32, 64);
    if (lane < 32 && srow < SN) atomicAdd(&scores_s[srow], part);
  }
  __syncthreads();

  // ---- phase 2: softmax in place (wave 0) ----
  if (wv == 0) {
    float v0[4];
    #pragma unroll
    for (int k = 0; k < 4; ++k) {
      int s = k * 64 + lane;
      v0[k] = (s < SN) ? scores_s[s] : -3.0e38f;
    }
    float m = fmaxf(fmaxf(v0[0], v0[1]), fmaxf(v0[2], v0[3]));
    #pragma unroll
    for (int off = 32; off >= 1; off >>= 1) m = fmaxf(m, __shfl_xor(m, off, 64));
    float e0[4], sum = 0.f;
    #pragma unroll
    for (int k = 0; k < 4; ++k) { e0[k] = __expf(v0[k] - m); sum += e0[k]; }
    #pragma unroll
    for (int off = 32; off >= 1; off >>= 1) sum += __shfl_xor(sum, off, 64);
    float inv = 1.0f / sum;
    #pragma unroll
    for (int k = 0; k < 4; ++k) {
      int s = k * 64 + lane;
      if (s < SN) scores_s[s] = e0[k] * inv;   // attn in place
    }
  }
  __syncthreads();

  // ---- phase 3: ui[e] = sum_s attn[s]*beh[s][e] ----
  {
    const int g  = tid & 15;
    const int sg = tid >> 4;                   // 0..15
    float ua[8] = {0.f,0.f,0.f,0.f,0.f,0.f,0.f,0.f};
    for (int s = sg; s < SN; s += 16) {
      float a = scores_s[s];
      const short8 bv = *(const short8*)((const char*)Abuf + aoff(s, g));
      #pragma unroll
      for (int j = 0; j < 8; ++j) ua[j] = fmaf(a, bf2f((unsigned short)bv[j]), ua[j]);
    }
    #pragma unroll
    for (int j = 0; j < 8; ++j) {
      ua[j] += __shfl_xor(ua[j], 16, 64);
      ua[j] += __shfl_xor(ua[j], 32, 64);
    }
    if (lane < 16) {
      #pragma unroll
      for (int j = 0; j < 8; ++j) atomicAdd(&ui_s[(g << 3) + j], ua[j]);
    }
  }
  __syncthreads();
  if (tid < EN) ws_ui[(size_t)b * EN + tid] = ui_s[tid];
}

// ---------------------------------------------------------------------------
// Kernel B: MLP head. Block = 4 batch rows (1024 blocks, 4/CU).
// ---------------------------------------------------------------------------
__global__ __launch_bounds__(256, 4)
void din_mlp(const float* __restrict__ ws_ui, const float* __restrict__ cand,
             const float* __restrict__ w1, const float* __restrict__ b1,
             const float* __restrict__ w2, const float* __restrict__ b2,
             float* __restrict__ out) {
  const int tid  = threadIdx.x;
  const int lane = tid & 63;
  const int wv   = tid >> 6;
  const int r0   = blockIdx.x * 4;

  float xr[4][4];
  #pragma unroll
  for (int r = 0; r < 4; ++r) {
    #pragma unroll
    for (int c = 0; c < 4; ++c) {
      int i = c * 64 + lane;
      int row = r0 + r;
      xr[r][c] = (i < 128) ? ws_ui[row * 128 + i] : cand[row * 128 + (i - 128)];
    }
  }

  const int j = tid;
  const float bj = b1[j];
  float acc[4] = {bj, bj, bj, bj};

  #pragma unroll
  for (int c = 0; c < 4; ++c) {
    #pragma unroll 8
    for (int il = 0; il < 64; ++il) {
      float w = w1[(c * 64 + il) * 256 + j];
      #pragma unroll
      for (int r = 0; r < 4; ++r)
        acc[r] = fmaf(bcast_lane(xr[r][c], il), w, acc[r]);
    }
  }

  const float w2j = w2[j];
  float part[4];
  #pragma unroll
  for (int r = 0; r < 4; ++r) part[r] = fmaxf(acc[r], 0.f) * w2j;
  #pragma unroll
  for (int off = 32; off >= 1; off >>= 1) {
    #pragma unroll
    for (int r = 0; r < 4; ++r) part[r] += __shfl_xor(part[r], off, 64);
  }

  __shared__ float red[4][4];
  if (lane == 0) {
    #pragma unroll
    for (int r = 0; r < 4; ++r) red[wv][r] = part[r];
  }
  __syncthreads();
  if (tid < 4)
    out[r0 + tid] = red[0][tid] + red[1][tid] + red[2][tid] + red[3][tid] + b2[0];
}

extern "C" void kernel_launch(void* const* d_in, const int* in_sizes, int n_in,
                              void* d_out, int out_size, void* d_ws, size_t ws_size,
                              hipStream_t stream) {
  const float* behavior = (const float*)d_in[0];
  const float* cand     = (const float*)d_in[1];
  const float* fc1w     = (const float*)d_in[2];
  const float* fc1b     = (const float*)d_in[3];
  const float* fc2w     = (const float*)d_in[4];
  // d_in[5] = fc2_b: constant shift before softmax -> softmax-invariant, skipped
  const float* m1w      = (const float*)d_in[6];
  const float* m1b      = (const float*)d_in[7];
  const float* m2w      = (const float*)d_in[8];
  const float* m2b      = (const float*)d_in[9];
  float* outp    = (float*)d_out;
  float* ws_ui   = (float*)d_ws;                                   // 2 MB
  short8* ws_afr = (short8*)((char*)d_ws + (size_t)BN * EN * 4);   // 32 KB

  din_prep<<<32, 64, 0, stream>>>(fc1w, ws_afr);
  din_attn<<<BN, 256, 0, stream>>>(behavior, cand, fc1w, fc1b, fc2w, ws_afr, ws_ui);
  din_mlp<<<BN / 4, 256, 0, stream>>>(ws_ui, cand, m1w, m1b, m2w, m2b, outp);
}